// Round 8
// baseline (427.289 us; speedup 1.0000x reference)
//
#include <hip/hip_runtime.h>

typedef unsigned short u16;
typedef __attribute__((ext_vector_type(8))) _Float16 f16x8;
typedef __attribute__((ext_vector_type(2))) __fp16 fp16v2;
typedef __attribute__((ext_vector_type(4))) float f32x4;
typedef __attribute__((ext_vector_type(16))) float f32x16;

#define T_SEQ 2048
#define NH 16
#define DH 64
#define DM 1024
// NEG * log2(e), masks applied in log2 domain (softmax via exp2)
#define NEG2 (-14426.95f)
// 64^-0.25 * sqrt(log2(e)) : folded so S^T comes out pre-scaled for exp2
#define QS2 (0.42466089f)

__device__ __forceinline__ unsigned pk2(float a, float b) {
  union { fp16v2 v; unsigned u; } c;
  c.v = __builtin_amdgcn_cvt_pkrtz(a, b);
  return c.u;
}
__device__ __forceinline__ u16 f2h(float a) {
  union { _Float16 h; u16 u; } c; c.h = (_Float16)a; return c.u;
}

// ---------------- fused QKV projection GEMM ----------------
// Reads fp32 activations/weights directly; fp32->fp16 convert fused into
// VGPR-mediated staging (loads for tile k+1 issued BEFORE barrier k, packed
// + ds_written after compute -> load latency hidden by a full iteration).
// which = n0>>10 selects input (q/k/v), weight, output.
// which<2 (Q/K): MFMA operands SWAPPED (row dim = channel); epilogue
//   LDS-transposes, stores [bh][t][dh] coalesced. QS2 scale folded.
// which==2 (V): normal order (row dim = t); stores VT [bh][dh][t] coalesced.
__global__ __launch_bounds__(256) void gemm_qkv(
    const float* __restrict__ Xq, const float* __restrict__ Xk, const float* __restrict__ Xv,
    const float* __restrict__ Wqf, const float* __restrict__ Wkf, const float* __restrict__ Wvf,
    u16* __restrict__ Qh, u16* __restrict__ Kh, u16* __restrict__ VTh) {
  __shared__ char lds[33792];  // dbuf staging 2x16KB; epilogue tile 128x264B aliases
  const int tid = threadIdx.x;
  const int wid = tid >> 6, lane = tid & 63;
  const int l32 = lane & 31, lh = lane >> 5;
  const int m0 = blockIdx.x * 128;
  const int n0 = blockIdx.y * 128;
  const int which = n0 >> 10;
  const int n0l = n0 & 1023;
  const float* Xs = (which == 0) ? Xq : (which == 1) ? Xk : Xv;
  const float* Wf = (which == 0) ? Wqf : (which == 1) ? Wkf : Wvf;
  const int wm = wid >> 1, wn = wid & 1;
  f32x16 acc[2][2] = {};

  // cell c = wid*2+ks (1KB): M[m0+wid*32+l32][kt+ks*16+lh*8 ..+8]
  const float* gA = Xs + (size_t)(m0 + wid * 32 + l32) * 1024 + lh * 8;
  const float* gB = Wf + (size_t)(n0l + wid * 32 + l32) * 1024 + lh * 8;

  // prologue: stage k-tile 0 into buffer 0
  {
    float4 a0 = *(const float4*)(gA), a1 = *(const float4*)(gA + 4);
    float4 a2 = *(const float4*)(gA + 16), a3 = *(const float4*)(gA + 20);
    float4 b0 = *(const float4*)(gB), b1 = *(const float4*)(gB + 4);
    float4 b2 = *(const float4*)(gB + 16), b3 = *(const float4*)(gB + 20);
    uint4 p;
    p.x = pk2(a0.x, a0.y); p.y = pk2(a0.z, a0.w); p.z = pk2(a1.x, a1.y); p.w = pk2(a1.z, a1.w);
    *(uint4*)(lds + (wid * 2 + 0) * 1024 + lane * 16) = p;
    p.x = pk2(a2.x, a2.y); p.y = pk2(a2.z, a2.w); p.z = pk2(a3.x, a3.y); p.w = pk2(a3.z, a3.w);
    *(uint4*)(lds + (wid * 2 + 1) * 1024 + lane * 16) = p;
    p.x = pk2(b0.x, b0.y); p.y = pk2(b0.z, b0.w); p.z = pk2(b1.x, b1.y); p.w = pk2(b1.z, b1.w);
    *(uint4*)(lds + 8192 + (wid * 2 + 0) * 1024 + lane * 16) = p;
    p.x = pk2(b2.x, b2.y); p.y = pk2(b2.z, b2.w); p.z = pk2(b3.x, b3.y); p.w = pk2(b3.z, b3.w);
    *(uint4*)(lds + 8192 + (wid * 2 + 1) * 1024 + lane * 16) = p;
  }

  for (int it = 0; it < 32; ++it) {
    float4 a0, a1, a2, a3, b0, b1, b2, b3;
    if (it < 31) {  // issue loads for tile k+1 BEFORE the barrier
      int kt = (it + 1) * 32;
      a0 = *(const float4*)(gA + kt);      a1 = *(const float4*)(gA + kt + 4);
      a2 = *(const float4*)(gA + kt + 16); a3 = *(const float4*)(gA + kt + 20);
      b0 = *(const float4*)(gB + kt);      b1 = *(const float4*)(gB + kt + 4);
      b2 = *(const float4*)(gB + kt + 16); b3 = *(const float4*)(gB + kt + 20);
    }
    __syncthreads();  // buf[it&1] writes visible; prev reads of buf[(it+1)&1] done
    char* cur = lds + ((it & 1) << 14);
    char* const rb = (which < 2) ? (cur + 8192) : cur;  // A-op: W for Q/K, X for V
    char* const cb = (which < 2) ? cur : (cur + 8192);
    for (int ks = 0; ks < 2; ++ks) {
      f16x8 rf[2], cf[2];
      for (int i = 0; i < 2; ++i) {
        rf[i] = *(const f16x8*)(rb + ((wm * 2 + i) * 2 + ks) * 1024 + lane * 16);
        cf[i] = *(const f16x8*)(cb + ((wn * 2 + i) * 2 + ks) * 1024 + lane * 16);
      }
      for (int i = 0; i < 2; ++i)
        for (int j = 0; j < 2; ++j)
          acc[i][j] = __builtin_amdgcn_mfma_f32_32x32x16_f16(rf[i], cf[j], acc[i][j], 0, 0, 0);
    }
    if (it < 31) {  // pack + write tile k+1 (vmcnt wait lands HERE, after compute)
      char* nxt = lds + (((it + 1) & 1) << 14);
      uint4 p;
      p.x = pk2(a0.x, a0.y); p.y = pk2(a0.z, a0.w); p.z = pk2(a1.x, a1.y); p.w = pk2(a1.z, a1.w);
      *(uint4*)(nxt + (wid * 2 + 0) * 1024 + lane * 16) = p;
      p.x = pk2(a2.x, a2.y); p.y = pk2(a2.z, a2.w); p.z = pk2(a3.x, a3.y); p.w = pk2(a3.z, a3.w);
      *(uint4*)(nxt + (wid * 2 + 1) * 1024 + lane * 16) = p;
      p.x = pk2(b0.x, b0.y); p.y = pk2(b0.z, b0.w); p.z = pk2(b1.x, b1.y); p.w = pk2(b1.z, b1.w);
      *(uint4*)(nxt + 8192 + (wid * 2 + 0) * 1024 + lane * 16) = p;
      p.x = pk2(b2.x, b2.y); p.y = pk2(b2.z, b2.w); p.z = pk2(b3.x, b3.y); p.w = pk2(b3.z, b3.w);
      *(uint4*)(nxt + 8192 + (wid * 2 + 1) * 1024 + lane * 16) = p;
    }
  }

  // epilogue: C/D row = (reg&3)+8*(reg>>2)+4*lh, col = l32.
  const float s = (which < 2) ? QS2 : 1.0f;
  __syncthreads();
  for (int i = 0; i < 2; ++i)
    for (int j = 0; j < 2; ++j) {
      int colb = wn * 64 + j * 32 + l32;
      int rowb = wm * 64 + i * 32 + 4 * lh;
      for (int g = 0; g < 4; ++g) {
        uint2 pv;
        pv.x = pk2(acc[i][j][4 * g + 0] * s, acc[i][j][4 * g + 1] * s);
        pv.y = pk2(acc[i][j][4 * g + 2] * s, acc[i][j][4 * g + 3] * s);
        *(uint2*)(lds + colb * 264 + (rowb + 8 * g) * 2) = pv;
      }
    }
  __syncthreads();

  const int b = m0 >> 11, t0 = m0 & 2047, h0 = n0l >> 6;
  if (which < 2) {
    u16* O = which ? Kh : Qh;
    for (int p = 0; p < 8; ++p) {
      int row = p * 16 + (tid >> 4);  // t_local
      int seg = tid & 15;
      uint4 val = *(const uint4*)(lds + row * 264 + seg * 16);
      int hl = seg >> 3, dh0 = (seg & 7) * 8;
      *(uint4*)(O + (((size_t)(b * NH + h0 + hl) * T_SEQ + t0 + row) << 6) + dh0) = val;
    }
  } else {
    for (int p = 0; p < 8; ++p) {
      int row = p * 16 + (tid >> 4);  // ch_local
      int seg = tid & 15;
      uint4 val = *(const uint4*)(lds + row * 264 + seg * 16);
      int h = h0 + (row >> 6), dh = row & 63;
      *(uint4*)(VTh + (((size_t)(b * NH + h) * DH + dh) << 11) + t0 + seg * 8) = val;
    }
  }
}

// ---------------- output projection GEMM (fp32 out) ----------------
// A = ctx fp16; B = Wo fp32 (convert fused into staging). Same dbuf scheme.
__global__ __launch_bounds__(256) void gemm_out(const u16* __restrict__ A,
                                                const float* __restrict__ WoF,
                                                float* __restrict__ O) {
  __shared__ char lds[32768];
  const int tid = threadIdx.x;
  const int wid = tid >> 6, lane = tid & 63;
  const int l32 = lane & 31, lh = lane >> 5;
  const int m0 = blockIdx.x * 128, n0 = blockIdx.y * 128;
  const int wm = wid >> 1, wn = wid & 1;
  f32x16 acc[2][2] = {};

  const u16* gA = A + (size_t)(m0 + wid * 32 + l32) * 1024 + lh * 8;
  const float* gB = WoF + (size_t)(n0 + wid * 32 + l32) * 1024 + lh * 8;

  {
    uint4 qa0 = *(const uint4*)(gA), qa1 = *(const uint4*)(gA + 16);
    float4 b0 = *(const float4*)(gB), b1 = *(const float4*)(gB + 4);
    float4 b2 = *(const float4*)(gB + 16), b3 = *(const float4*)(gB + 20);
    *(uint4*)(lds + (wid * 2 + 0) * 1024 + lane * 16) = qa0;
    *(uint4*)(lds + (wid * 2 + 1) * 1024 + lane * 16) = qa1;
    uint4 p;
    p.x = pk2(b0.x, b0.y); p.y = pk2(b0.z, b0.w); p.z = pk2(b1.x, b1.y); p.w = pk2(b1.z, b1.w);
    *(uint4*)(lds + 8192 + (wid * 2 + 0) * 1024 + lane * 16) = p;
    p.x = pk2(b2.x, b2.y); p.y = pk2(b2.z, b2.w); p.z = pk2(b3.x, b3.y); p.w = pk2(b3.z, b3.w);
    *(uint4*)(lds + 8192 + (wid * 2 + 1) * 1024 + lane * 16) = p;
  }

  for (int it = 0; it < 32; ++it) {
    uint4 qa0, qa1;
    float4 b0, b1, b2, b3;
    if (it < 31) {
      int kt = (it + 1) * 32;
      qa0 = *(const uint4*)(gA + kt); qa1 = *(const uint4*)(gA + kt + 16);
      b0 = *(const float4*)(gB + kt);      b1 = *(const float4*)(gB + kt + 4);
      b2 = *(const float4*)(gB + kt + 16); b3 = *(const float4*)(gB + kt + 20);
    }
    __syncthreads();
    char* cur = lds + ((it & 1) << 14);
    for (int ks = 0; ks < 2; ++ks) {
      f16x8 af[2], bf[2];
      for (int i = 0; i < 2; ++i) {
        af[i] = *(const f16x8*)(cur + ((wm * 2 + i) * 2 + ks) * 1024 + lane * 16);
        bf[i] = *(const f16x8*)(cur + 8192 + ((wn * 2 + i) * 2 + ks) * 1024 + lane * 16);
      }
      for (int i = 0; i < 2; ++i)
        for (int j = 0; j < 2; ++j)
          acc[i][j] = __builtin_amdgcn_mfma_f32_32x32x16_f16(af[i], bf[j], acc[i][j], 0, 0, 0);
    }
    if (it < 31) {
      char* nxt = lds + (((it + 1) & 1) << 14);
      *(uint4*)(nxt + (wid * 2 + 0) * 1024 + lane * 16) = qa0;
      *(uint4*)(nxt + (wid * 2 + 1) * 1024 + lane * 16) = qa1;
      uint4 p;
      p.x = pk2(b0.x, b0.y); p.y = pk2(b0.z, b0.w); p.z = pk2(b1.x, b1.y); p.w = pk2(b1.z, b1.w);
      *(uint4*)(nxt + 8192 + (wid * 2 + 0) * 1024 + lane * 16) = p;
      p.x = pk2(b2.x, b2.y); p.y = pk2(b2.z, b2.w); p.z = pk2(b3.x, b3.y); p.w = pk2(b3.z, b3.w);
      *(uint4*)(nxt + 8192 + (wid * 2 + 1) * 1024 + lane * 16) = p;
    }
  }
  for (int i = 0; i < 2; ++i)
    for (int j = 0; j < 2; ++j) {
      int col = n0 + wn * 64 + j * 32 + l32;
      int rowb = m0 + wm * 64 + i * 32 + 4 * lh;
      for (int g = 0; g < 4; ++g)
        for (int rr = 0; rr < 4; ++rr)
          O[(size_t)(rowb + 8 * g + rr) * 1024 + col] = acc[i][j][4 * g + rr];
    }
}

// ---------------- Flash attention (S^T, fp16, 8 waves, dbuf K/V) ----------------
// Qh/Kh: f16 [bh][t][64] pre-scaled by QS2. VTh: f16 [bh][dh][t].
// ctx out: f16 [b][t][1024]. Block = 512 thr, q-tile 128; pair (p8, 15-p8).
// K/V chunks staged via VGPR (uint4) with ONE barrier per chunk.
__global__ __launch_bounds__(512) void attn_kernel(const u16* __restrict__ Qh,
                                                   const u16* __restrict__ Kh,
                                                   const u16* __restrict__ VTh,
                                                   const float* __restrict__ attn_mask,
                                                   const int* __restrict__ mfp,
                                                   u16* __restrict__ ctx) {
  __shared__ char kls[2][8192];   // K chunk (64s x 64k), cells (st*2+kk)
  __shared__ char vls[2][8192];   // V^T chunk (64dh x 64s), cells (nt*2+kk)
  __shared__ char pls[8][2048];   // per-wave P (16q x 64s) in A-frag order
  __shared__ u16 maskb[T_SEQ];    // pad bias in log2 domain (f16)
  __shared__ int mzf;             // 1 if any pad-mask zero for this b

  const int tid = threadIdx.x;
  const int wid = tid >> 6, lane = tid & 63;
  const int lm = lane & 15, lq = lane >> 4;
  const int bid = blockIdx.x;
  const int bh_i = bid & 63, p8 = bid >> 6;
  const int b = bh_i >> 4, h = bh_i & 15;
  const int mf = *mfp;
  const size_t bh = (size_t)(b * NH + h);
  const u16* Qbh = Qh + bh * T_SEQ * DH;
  const u16* Kbh = Kh + bh * T_SEQ * DH;
  const u16* VTbh = VTh + bh * DH * T_SEQ;

  if (tid == 0) mzf = 0;
  __syncthreads();
  {
    int az = 0;
    for (int i = tid; i < T_SEQ; i += 512) {
      float mv = attn_mask[(size_t)b * T_SEQ + i];
      maskb[i] = f2h((mv == 0.0f) ? NEG2 : 0.0f);
      az |= (mv == 0.0f);
    }
    if (az) mzf = 1;  // benign same-value race
  }
  __syncthreads();
  const int maskzero = mzf;

  const int krow = (wid >> 1) * 16 + lm, koff = (wid & 1) * 32 + lq * 8;

  for (int half = 0; half < 2; ++half) {
    const int qt = half ? (15 - p8) : p8;   // 128-row q-tile index
    const int q0 = qt * 128;
    const int qw = q0 + wid * 16;
    f16x8 qf[2];
    qf[0] = *(const f16x8*)(Qbh + (size_t)(qw + lm) * DH + lq * 8);
    qf[1] = *(const f16x8*)(Qbh + (size_t)(qw + lm) * DH + 32 + lq * 8);

    f32x4 acc[4] = {};                // O: row=q_loc(lq*4+r), col=dh(nt*16+lm)
    float mprev = -1e30f, lsum = 0.f; // state for q = qw+lm (replicated over lq)

    const int nch = mf ? (qt + 1) * 2 : 32;
    // prologue: chunk 0 -> buf 0 (barrier first: prev half may still read kls/vls)
    uint4 kv = *(const uint4*)(Kbh + (size_t)(0 + krow) * DH + koff);
    uint4 vv = *(const uint4*)(VTbh + (size_t)krow * T_SEQ + 0 + koff);
    __syncthreads();
    *(uint4*)(kls[0] + wid * 1024 + lane * 16) = kv;
    *(uint4*)(vls[0] + wid * 1024 + lane * 16) = vv;

    for (int c = 0; c < nch; ++c) {
      const int s0 = c * 64;
      if (c + 1 < nch) {  // issue next-chunk loads BEFORE the barrier
        int s1 = s0 + 64;
        kv = *(const uint4*)(Kbh + (size_t)(s1 + krow) * DH + koff);
        vv = *(const uint4*)(VTbh + (size_t)krow * T_SEQ + s1 + koff);
      }
      __syncthreads();
      const char* kb = kls[c & 1];
      const char* vb = vls[c & 1];

      // S^T tiles: A=K (m=s), B=Q (n=q). sc[st]: row s_loc=lq*4+r, col q=qw+lm
      f32x4 sc[4];
      for (int st = 0; st < 4; ++st) {
        f32x4 z = {0.f, 0.f, 0.f, 0.f};
        sc[st] = z;
        for (int kk = 0; kk < 2; ++kk) {
          f16x8 kf = *(const f16x8*)(kb + ((st * 2 + kk) * 64 + lane) * 16);
          sc[st] = __builtin_amdgcn_mfma_f32_16x16x32_f16(kf, qf[kk], sc[st], 0, 0, 0);
        }
      }
      if (maskzero) {
        for (int st = 0; st < 4; ++st) {
          uint2 mraw = *(const uint2*)(maskb + s0 + st * 16 + lq * 4);
          const _Float16* mh = (const _Float16*)&mraw;
          for (int r = 0; r < 4; ++r) sc[st][r] += (float)mh[r];
        }
      }
      if (mf && (s0 + 64 > qw)) {
        int qg = qw + lm;
        for (int st = 0; st < 4; ++st)
          for (int r = 0; r < 4; ++r)
            if (s0 + st * 16 + lq * 4 + r > qg) sc[st][r] = NEG2;
      }
      // online softmax over s: chunk max, then conditional rescale
      float mx = fmaxf(fmaxf(sc[0][0], sc[0][1]), fmaxf(sc[0][2], sc[0][3]));
      for (int st = 1; st < 4; ++st) {
        float t2 = fmaxf(fmaxf(sc[st][0], sc[st][1]), fmaxf(sc[st][2], sc[st][3]));
        mx = fmaxf(mx, t2);
      }
      mx = fmaxf(mx, __shfl_xor(mx, 16));
      mx = fmaxf(mx, __shfl_xor(mx, 32));
      float mn = mprev;
      if (__ballot(mx > mprev) != 0ull) {
        mn = fmaxf(mprev, mx);
        float alpha = exp2f(mprev - mn);
        for (int r = 0; r < 4; ++r) {
          float ar = __shfl(alpha, lq * 4 + r);
          for (int nt = 0; nt < 4; ++nt) acc[nt][r] *= ar;
        }
        lsum *= alpha;
        mprev = mn;
      }
      float ps = 0.f;
      for (int st = 0; st < 4; ++st)
        for (int r = 0; r < 4; ++r) {
          float p = exp2f(sc[st][r] - mn);
          sc[st][r] = p;
          ps += p;
        }
      ps += __shfl_xor(ps, 16);
      ps += __shfl_xor(ps, 32);
      lsum += ps;
      // P -> per-wave LDS in A-frag order (wave-local round trip)
      {
        char* pw = pls[wid];
        for (int st = 0; st < 4; ++st) {
          int kk = st >> 1;
          int lqp = (st & 1) * 2 + (lq >> 1);
          uint2 pv;
          pv.x = pk2(sc[st][0], sc[st][1]);
          pv.y = pk2(sc[st][2], sc[st][3]);
          *(uint2*)(pw + kk * 1024 + (lqp * 16 + lm) * 16 + (lq & 1) * 8) = pv;
        }
      }
      asm volatile("s_waitcnt lgkmcnt(0)" ::: "memory");
      for (int kk = 0; kk < 2; ++kk) {
        f16x8 pf = *(const f16x8*)(pls[wid] + kk * 1024 + lane * 16);
        for (int nt = 0; nt < 4; ++nt) {
          f16x8 vf = *(const f16x8*)(vb + ((nt * 2 + kk) * 64 + lane) * 16);
          acc[nt] = __builtin_amdgcn_mfma_f32_16x16x32_f16(pf, vf, acc[nt], 0, 0, 0);
        }
      }
      if (c + 1 < nch) {  // stage next chunk into the other buffer
        *(uint4*)(kls[(c + 1) & 1] + wid * 1024 + lane * 16) = kv;
        *(uint4*)(vls[(c + 1) & 1] + wid * 1024 + lane * 16) = vv;
      }
    }
    // epilogue: ctx[b][t][h*64+dh] f16
    float inv = 1.0f / lsum;
    for (int r = 0; r < 4; ++r) {
      float ir = __shfl(inv, lq * 4 + r);
      int t = qw + lq * 4 + r;
      for (int nt = 0; nt < 4; ++nt)
        ctx[((size_t)(b * T_SEQ + t) * DM) + h * DH + nt * 16 + lm] = f2h(acc[nt][r] * ir);
    }
  }
}

extern "C" void kernel_launch(void* const* d_in, const int* in_sizes, int n_in,
                              void* d_out, int out_size, void* d_ws, size_t ws_size,
                              hipStream_t stream) {
  const float* q = (const float*)d_in[0];
  const float* k = (const float*)d_in[1];
  const float* v = (const float*)d_in[2];
  const float* attn_mask = (const float*)d_in[3];
  const float* Wq = (const float*)d_in[4];
  const float* Wk = (const float*)d_in[5];
  const float* Wv = (const float*)d_in[6];
  const float* Wo = (const float*)d_in[7];
  const int* mf = (const int*)d_in[8];

  u16* ws = (u16*)d_ws;
  u16* ctxb = ws;                     // f16 [8192][1024]
  u16* Qh  = ws + 8388608u;           // f16 [bh][t][64]
  u16* Kh  = Qh + 8388608u;           // f16 [bh][t][64]
  u16* VTh = Kh + 8388608u;           // f16 [bh][dh][2048]

  dim3 gq(64, 24);
  gemm_qkv<<<gq, 256, 0, stream>>>(q, k, v, Wq, Wk, Wv, Qh, Kh, VTh);

  attn_kernel<<<512, 512, 0, stream>>>(Qh, Kh, VTh, attn_mask, mf, ctxb);

  dim3 gg(64, 8);
  gemm_out<<<gg, 256, 0, stream>>>(ctxb, Wo, (float*)d_out);
}

// Round 9
// 426.759 us; speedup vs baseline: 1.0012x; 1.0012x over previous
//
#include <hip/hip_runtime.h>

typedef unsigned short u16;
typedef __attribute__((ext_vector_type(8))) _Float16 f16x8;
typedef __attribute__((ext_vector_type(2))) __fp16 fp16v2;
typedef __attribute__((ext_vector_type(4))) float f32x4;
typedef __attribute__((ext_vector_type(16))) float f32x16;

#define T_SEQ 2048
#define NH 16
#define DH 64
#define DM 1024
// NEG * log2(e), masks applied in log2 domain (softmax via exp2)
#define NEG2 (-14426.95f)
// 64^-0.25 * sqrt(log2(e)) : folded so S^T comes out pre-scaled for exp2
#define QS2 (0.42466089f)

__device__ __forceinline__ unsigned pk2(float a, float b) {
  union { fp16v2 v; unsigned u; } c;
  c.v = __builtin_amdgcn_cvt_pkrtz(a, b);
  return c.u;
}
__device__ __forceinline__ u16 f2h(float a) {
  union { _Float16 h; u16 u; } c; c.h = (_Float16)a; return c.u;
}

// Barrier that drains ONLY LDS ops (own wave) — in-flight global loads
// survive and drain at their first use. This is the piece __syncthreads
// cannot express (it emits s_waitcnt vmcnt(0) before s_barrier).
__device__ __forceinline__ void lgkm_barrier() {
  asm volatile("s_waitcnt lgkmcnt(0)\n\ts_barrier" ::: "memory");
}

// ---------------- fused QKV projection GEMM ----------------
// Reads fp32 activations/weights directly; fp32->fp16 convert fused into
// VGPR-mediated staging. Loads for tile k+1 issued BEFORE the (lgkm-only)
// barrier; their vmcnt wait lands at the pack/ds_write AFTER tile-k compute.
// which<2 (Q/K): MFMA operands SWAPPED (row dim = channel); epilogue
//   LDS-transposes, stores [bh][t][dh] coalesced. QS2 scale folded.
// which==2 (V): normal order (row dim = t); stores VT [bh][dh][t] coalesced.
__global__ __launch_bounds__(256) void gemm_qkv(
    const float* __restrict__ Xq, const float* __restrict__ Xk, const float* __restrict__ Xv,
    const float* __restrict__ Wqf, const float* __restrict__ Wkf, const float* __restrict__ Wvf,
    u16* __restrict__ Qh, u16* __restrict__ Kh, u16* __restrict__ VTh) {
  __shared__ char lds[33792];  // dbuf staging 2x16KB; epilogue tile 128x264B aliases
  const int tid = threadIdx.x;
  const int wid = tid >> 6, lane = tid & 63;
  const int l32 = lane & 31, lh = lane >> 5;
  const int m0 = blockIdx.x * 128;
  const int n0 = blockIdx.y * 128;
  const int which = n0 >> 10;
  const int n0l = n0 & 1023;
  const float* Xs = (which == 0) ? Xq : (which == 1) ? Xk : Xv;
  const float* Wf = (which == 0) ? Wqf : (which == 1) ? Wkf : Wvf;
  const int wm = wid >> 1, wn = wid & 1;
  f32x16 acc[2][2] = {};

  // cell c = wid*2+ks (1KB): M[m0+wid*32+l32][kt+ks*16+lh*8 ..+8]
  const float* gA = Xs + (size_t)(m0 + wid * 32 + l32) * 1024 + lh * 8;
  const float* gB = Wf + (size_t)(n0l + wid * 32 + l32) * 1024 + lh * 8;

  // prologue: stage k-tile 0 into buffer 0
  {
    float4 a0 = *(const float4*)(gA), a1 = *(const float4*)(gA + 4);
    float4 a2 = *(const float4*)(gA + 16), a3 = *(const float4*)(gA + 20);
    float4 b0 = *(const float4*)(gB), b1 = *(const float4*)(gB + 4);
    float4 b2 = *(const float4*)(gB + 16), b3 = *(const float4*)(gB + 20);
    uint4 p;
    p.x = pk2(a0.x, a0.y); p.y = pk2(a0.z, a0.w); p.z = pk2(a1.x, a1.y); p.w = pk2(a1.z, a1.w);
    *(uint4*)(lds + (wid * 2 + 0) * 1024 + lane * 16) = p;
    p.x = pk2(a2.x, a2.y); p.y = pk2(a2.z, a2.w); p.z = pk2(a3.x, a3.y); p.w = pk2(a3.z, a3.w);
    *(uint4*)(lds + (wid * 2 + 1) * 1024 + lane * 16) = p;
    p.x = pk2(b0.x, b0.y); p.y = pk2(b0.z, b0.w); p.z = pk2(b1.x, b1.y); p.w = pk2(b1.z, b1.w);
    *(uint4*)(lds + 8192 + (wid * 2 + 0) * 1024 + lane * 16) = p;
    p.x = pk2(b2.x, b2.y); p.y = pk2(b2.z, b2.w); p.z = pk2(b3.x, b3.y); p.w = pk2(b3.z, b3.w);
    *(uint4*)(lds + 8192 + (wid * 2 + 1) * 1024 + lane * 16) = p;
  }

  for (int it = 0; it < 32; ++it) {
    float4 a0, a1, a2, a3, b0, b1, b2, b3;
    if (it < 31) {  // issue loads for tile k+1; they stay in flight across barrier
      int kt = (it + 1) * 32;
      a0 = *(const float4*)(gA + kt);      a1 = *(const float4*)(gA + kt + 4);
      a2 = *(const float4*)(gA + kt + 16); a3 = *(const float4*)(gA + kt + 20);
      b0 = *(const float4*)(gB + kt);      b1 = *(const float4*)(gB + kt + 4);
      b2 = *(const float4*)(gB + kt + 16); b3 = *(const float4*)(gB + kt + 20);
    }
    lgkm_barrier();  // LDS-only drain: buf[it&1] writes visible, loads survive
    char* cur = lds + ((it & 1) << 14);
    char* const rb = (which < 2) ? (cur + 8192) : cur;  // A-op: W for Q/K, X for V
    char* const cb = (which < 2) ? cur : (cur + 8192);
    for (int ks = 0; ks < 2; ++ks) {
      f16x8 rf[2], cf[2];
      for (int i = 0; i < 2; ++i) {
        rf[i] = *(const f16x8*)(rb + ((wm * 2 + i) * 2 + ks) * 1024 + lane * 16);
        cf[i] = *(const f16x8*)(cb + ((wn * 2 + i) * 2 + ks) * 1024 + lane * 16);
      }
      for (int i = 0; i < 2; ++i)
        for (int j = 0; j < 2; ++j)
          acc[i][j] = __builtin_amdgcn_mfma_f32_32x32x16_f16(rf[i], cf[j], acc[i][j], 0, 0, 0);
    }
    if (it < 31) {  // vmcnt wait lands HERE, after a full compute phase
      char* nxt = lds + (((it + 1) & 1) << 14);
      uint4 p;
      p.x = pk2(a0.x, a0.y); p.y = pk2(a0.z, a0.w); p.z = pk2(a1.x, a1.y); p.w = pk2(a1.z, a1.w);
      *(uint4*)(nxt + (wid * 2 + 0) * 1024 + lane * 16) = p;
      p.x = pk2(a2.x, a2.y); p.y = pk2(a2.z, a2.w); p.z = pk2(a3.x, a3.y); p.w = pk2(a3.z, a3.w);
      *(uint4*)(nxt + (wid * 2 + 1) * 1024 + lane * 16) = p;
      p.x = pk2(b0.x, b0.y); p.y = pk2(b0.z, b0.w); p.z = pk2(b1.x, b1.y); p.w = pk2(b1.z, b1.w);
      *(uint4*)(nxt + 8192 + (wid * 2 + 0) * 1024 + lane * 16) = p;
      p.x = pk2(b2.x, b2.y); p.y = pk2(b2.z, b2.w); p.z = pk2(b3.x, b3.y); p.w = pk2(b3.z, b3.w);
      *(uint4*)(nxt + 8192 + (wid * 2 + 1) * 1024 + lane * 16) = p;
    }
  }

  // epilogue: C/D row = (reg&3)+8*(reg>>2)+4*lh, col = l32.
  const float s = (which < 2) ? QS2 : 1.0f;
  __syncthreads();
  for (int i = 0; i < 2; ++i)
    for (int j = 0; j < 2; ++j) {
      int colb = wn * 64 + j * 32 + l32;
      int rowb = wm * 64 + i * 32 + 4 * lh;
      for (int g = 0; g < 4; ++g) {
        uint2 pv;
        pv.x = pk2(acc[i][j][4 * g + 0] * s, acc[i][j][4 * g + 1] * s);
        pv.y = pk2(acc[i][j][4 * g + 2] * s, acc[i][j][4 * g + 3] * s);
        *(uint2*)(lds + colb * 264 + (rowb + 8 * g) * 2) = pv;
      }
    }
  __syncthreads();

  const int b = m0 >> 11, t0 = m0 & 2047, h0 = n0l >> 6;
  if (which < 2) {
    u16* O = which ? Kh : Qh;
    for (int p = 0; p < 8; ++p) {
      int row = p * 16 + (tid >> 4);  // t_local
      int seg = tid & 15;
      uint4 val = *(const uint4*)(lds + row * 264 + seg * 16);
      int hl = seg >> 3, dh0 = (seg & 7) * 8;
      *(uint4*)(O + (((size_t)(b * NH + h0 + hl) * T_SEQ + t0 + row) << 6) + dh0) = val;
    }
  } else {
    for (int p = 0; p < 8; ++p) {
      int row = p * 16 + (tid >> 4);  // ch_local
      int seg = tid & 15;
      uint4 val = *(const uint4*)(lds + row * 264 + seg * 16);
      int h = h0 + (row >> 6), dh = row & 63;
      *(uint4*)(VTh + (((size_t)(b * NH + h) * DH + dh) << 11) + t0 + seg * 8) = val;
    }
  }
}

// ---------------- output projection GEMM (fp32 out) ----------------
// A = ctx fp16; B = Wo fp32 (convert fused into staging). Same dbuf scheme.
__global__ __launch_bounds__(256) void gemm_out(const u16* __restrict__ A,
                                                const float* __restrict__ WoF,
                                                float* __restrict__ O) {
  __shared__ char lds[32768];
  const int tid = threadIdx.x;
  const int wid = tid >> 6, lane = tid & 63;
  const int l32 = lane & 31, lh = lane >> 5;
  const int m0 = blockIdx.x * 128, n0 = blockIdx.y * 128;
  const int wm = wid >> 1, wn = wid & 1;
  f32x16 acc[2][2] = {};

  const u16* gA = A + (size_t)(m0 + wid * 32 + l32) * 1024 + lh * 8;
  const float* gB = WoF + (size_t)(n0 + wid * 32 + l32) * 1024 + lh * 8;

  {
    uint4 qa0 = *(const uint4*)(gA), qa1 = *(const uint4*)(gA + 16);
    float4 b0 = *(const float4*)(gB), b1 = *(const float4*)(gB + 4);
    float4 b2 = *(const float4*)(gB + 16), b3 = *(const float4*)(gB + 20);
    *(uint4*)(lds + (wid * 2 + 0) * 1024 + lane * 16) = qa0;
    *(uint4*)(lds + (wid * 2 + 1) * 1024 + lane * 16) = qa1;
    uint4 p;
    p.x = pk2(b0.x, b0.y); p.y = pk2(b0.z, b0.w); p.z = pk2(b1.x, b1.y); p.w = pk2(b1.z, b1.w);
    *(uint4*)(lds + 8192 + (wid * 2 + 0) * 1024 + lane * 16) = p;
    p.x = pk2(b2.x, b2.y); p.y = pk2(b2.z, b2.w); p.z = pk2(b3.x, b3.y); p.w = pk2(b3.z, b3.w);
    *(uint4*)(lds + 8192 + (wid * 2 + 1) * 1024 + lane * 16) = p;
  }

  for (int it = 0; it < 32; ++it) {
    uint4 qa0, qa1;
    float4 b0, b1, b2, b3;
    if (it < 31) {
      int kt = (it + 1) * 32;
      qa0 = *(const uint4*)(gA + kt); qa1 = *(const uint4*)(gA + kt + 16);
      b0 = *(const float4*)(gB + kt);      b1 = *(const float4*)(gB + kt + 4);
      b2 = *(const float4*)(gB + kt + 16); b3 = *(const float4*)(gB + kt + 20);
    }
    lgkm_barrier();
    char* cur = lds + ((it & 1) << 14);
    for (int ks = 0; ks < 2; ++ks) {
      f16x8 af[2], bf[2];
      for (int i = 0; i < 2; ++i) {
        af[i] = *(const f16x8*)(cur + ((wm * 2 + i) * 2 + ks) * 1024 + lane * 16);
        bf[i] = *(const f16x8*)(cur + 8192 + ((wn * 2 + i) * 2 + ks) * 1024 + lane * 16);
      }
      for (int i = 0; i < 2; ++i)
        for (int j = 0; j < 2; ++j)
          acc[i][j] = __builtin_amdgcn_mfma_f32_32x32x16_f16(af[i], bf[j], acc[i][j], 0, 0, 0);
    }
    if (it < 31) {
      char* nxt = lds + (((it + 1) & 1) << 14);
      *(uint4*)(nxt + (wid * 2 + 0) * 1024 + lane * 16) = qa0;
      *(uint4*)(nxt + (wid * 2 + 1) * 1024 + lane * 16) = qa1;
      uint4 p;
      p.x = pk2(b0.x, b0.y); p.y = pk2(b0.z, b0.w); p.z = pk2(b1.x, b1.y); p.w = pk2(b1.z, b1.w);
      *(uint4*)(nxt + 8192 + (wid * 2 + 0) * 1024 + lane * 16) = p;
      p.x = pk2(b2.x, b2.y); p.y = pk2(b2.z, b2.w); p.z = pk2(b3.x, b3.y); p.w = pk2(b3.z, b3.w);
      *(uint4*)(nxt + 8192 + (wid * 2 + 1) * 1024 + lane * 16) = p;
    }
  }
  for (int i = 0; i < 2; ++i)
    for (int j = 0; j < 2; ++j) {
      int col = n0 + wn * 64 + j * 32 + l32;
      int rowb = m0 + wm * 64 + i * 32 + 4 * lh;
      for (int g = 0; g < 4; ++g)
        for (int rr = 0; rr < 4; ++rr)
          O[(size_t)(rowb + 8 * g + rr) * 1024 + col] = acc[i][j][4 * g + rr];
    }
}

// ---------------- Flash attention (S^T, fp16, 8 waves, dbuf K/V) ----------------
// Qh/Kh: f16 [bh][t][64] pre-scaled by QS2. VTh: f16 [bh][dh][t].
// ctx out: f16 [b][t][1024]. Block = 512 thr, q-tile 128; pair (p8, 15-p8).
// K/V chunks staged via VGPR (uint4); lgkm-only barrier keeps loads in flight.
__global__ __launch_bounds__(512) void attn_kernel(const u16* __restrict__ Qh,
                                                   const u16* __restrict__ Kh,
                                                   const u16* __restrict__ VTh,
                                                   const float* __restrict__ attn_mask,
                                                   const int* __restrict__ mfp,
                                                   u16* __restrict__ ctx) {
  __shared__ char kls[2][8192];   // K chunk (64s x 64k), cells (st*2+kk)
  __shared__ char vls[2][8192];   // V^T chunk (64dh x 64s), cells (nt*2+kk)
  __shared__ char pls[8][2048];   // per-wave P (16q x 64s) in A-frag order
  __shared__ u16 maskb[T_SEQ];    // pad bias in log2 domain (f16)
  __shared__ int mzf;             // 1 if any pad-mask zero for this b

  const int tid = threadIdx.x;
  const int wid = tid >> 6, lane = tid & 63;
  const int lm = lane & 15, lq = lane >> 4;
  const int bid = blockIdx.x;
  const int bh_i = bid & 63, p8 = bid >> 6;
  const int b = bh_i >> 4, h = bh_i & 15;
  const int mf = *mfp;
  const size_t bh = (size_t)(b * NH + h);
  const u16* Qbh = Qh + bh * T_SEQ * DH;
  const u16* Kbh = Kh + bh * T_SEQ * DH;
  const u16* VTbh = VTh + bh * DH * T_SEQ;

  if (tid == 0) mzf = 0;
  __syncthreads();
  {
    int az = 0;
    for (int i = tid; i < T_SEQ; i += 512) {
      float mv = attn_mask[(size_t)b * T_SEQ + i];
      maskb[i] = f2h((mv == 0.0f) ? NEG2 : 0.0f);
      az |= (mv == 0.0f);
    }
    if (az) mzf = 1;  // benign same-value race
  }
  __syncthreads();
  const int maskzero = mzf;

  const int krow = (wid >> 1) * 16 + lm, koff = (wid & 1) * 32 + lq * 8;

  for (int half = 0; half < 2; ++half) {
    const int qt = half ? (15 - p8) : p8;   // 128-row q-tile index
    const int q0 = qt * 128;
    const int qw = q0 + wid * 16;
    f16x8 qf[2];
    qf[0] = *(const f16x8*)(Qbh + (size_t)(qw + lm) * DH + lq * 8);
    qf[1] = *(const f16x8*)(Qbh + (size_t)(qw + lm) * DH + 32 + lq * 8);

    f32x4 acc[4] = {};                // O: row=q_loc(lq*4+r), col=dh(nt*16+lm)
    float mprev = -1e30f, lsum = 0.f; // state for q = qw+lm (replicated over lq)

    const int nch = mf ? (qt + 1) * 2 : 32;
    // prologue: chunk 0 -> buf 0 (barrier first: prev half may still read kls/vls)
    uint4 kv = *(const uint4*)(Kbh + (size_t)(0 + krow) * DH + koff);
    uint4 vv = *(const uint4*)(VTbh + (size_t)krow * T_SEQ + 0 + koff);
    lgkm_barrier();
    *(uint4*)(kls[0] + wid * 1024 + lane * 16) = kv;
    *(uint4*)(vls[0] + wid * 1024 + lane * 16) = vv;

    for (int c = 0; c < nch; ++c) {
      const int s0 = c * 64;
      if (c + 1 < nch) {  // next-chunk loads stay in flight across the barrier
        int s1 = s0 + 64;
        kv = *(const uint4*)(Kbh + (size_t)(s1 + krow) * DH + koff);
        vv = *(const uint4*)(VTbh + (size_t)krow * T_SEQ + s1 + koff);
      }
      lgkm_barrier();
      const char* kb = kls[c & 1];
      const char* vb = vls[c & 1];

      // S^T tiles: A=K (m=s), B=Q (n=q). sc[st]: row s_loc=lq*4+r, col q=qw+lm
      f32x4 sc[4];
      for (int st = 0; st < 4; ++st) {
        f32x4 z = {0.f, 0.f, 0.f, 0.f};
        sc[st] = z;
        for (int kk = 0; kk < 2; ++kk) {
          f16x8 kf = *(const f16x8*)(kb + ((st * 2 + kk) * 64 + lane) * 16);
          sc[st] = __builtin_amdgcn_mfma_f32_16x16x32_f16(kf, qf[kk], sc[st], 0, 0, 0);
        }
      }
      if (maskzero) {
        for (int st = 0; st < 4; ++st) {
          uint2 mraw = *(const uint2*)(maskb + s0 + st * 16 + lq * 4);
          const _Float16* mh = (const _Float16*)&mraw;
          for (int r = 0; r < 4; ++r) sc[st][r] += (float)mh[r];
        }
      }
      if (mf && (s0 + 64 > qw)) {
        int qg = qw + lm;
        for (int st = 0; st < 4; ++st)
          for (int r = 0; r < 4; ++r)
            if (s0 + st * 16 + lq * 4 + r > qg) sc[st][r] = NEG2;
      }
      // online softmax over s: chunk max, then conditional rescale
      float mx = fmaxf(fmaxf(sc[0][0], sc[0][1]), fmaxf(sc[0][2], sc[0][3]));
      for (int st = 1; st < 4; ++st) {
        float t2 = fmaxf(fmaxf(sc[st][0], sc[st][1]), fmaxf(sc[st][2], sc[st][3]));
        mx = fmaxf(mx, t2);
      }
      mx = fmaxf(mx, __shfl_xor(mx, 16));
      mx = fmaxf(mx, __shfl_xor(mx, 32));
      float mn = mprev;
      if (__ballot(mx > mprev) != 0ull) {
        mn = fmaxf(mprev, mx);
        float alpha = exp2f(mprev - mn);
        for (int r = 0; r < 4; ++r) {
          float ar = __shfl(alpha, lq * 4 + r);
          for (int nt = 0; nt < 4; ++nt) acc[nt][r] *= ar;
        }
        lsum *= alpha;
        mprev = mn;
      }
      float ps = 0.f;
      for (int st = 0; st < 4; ++st)
        for (int r = 0; r < 4; ++r) {
          float p = exp2f(sc[st][r] - mn);
          sc[st][r] = p;
          ps += p;
        }
      ps += __shfl_xor(ps, 16);
      ps += __shfl_xor(ps, 32);
      lsum += ps;
      // P -> per-wave LDS in A-frag order (wave-local round trip)
      {
        char* pw = pls[wid];
        for (int st = 0; st < 4; ++st) {
          int kk = st >> 1;
          int lqp = (st & 1) * 2 + (lq >> 1);
          uint2 pv;
          pv.x = pk2(sc[st][0], sc[st][1]);
          pv.y = pk2(sc[st][2], sc[st][3]);
          *(uint2*)(pw + kk * 1024 + (lqp * 16 + lm) * 16 + (lq & 1) * 8) = pv;
        }
      }
      asm volatile("s_waitcnt lgkmcnt(0)" ::: "memory");
      for (int kk = 0; kk < 2; ++kk) {
        f16x8 pf = *(const f16x8*)(pls[wid] + kk * 1024 + lane * 16);
        for (int nt = 0; nt < 4; ++nt) {
          f16x8 vf = *(const f16x8*)(vb + ((nt * 2 + kk) * 64 + lane) * 16);
          acc[nt] = __builtin_amdgcn_mfma_f32_16x16x32_f16(pf, vf, acc[nt], 0, 0, 0);
        }
      }
      if (c + 1 < nch) {  // vmcnt wait for kv/vv lands here, after full chunk compute
        *(uint4*)(kls[(c + 1) & 1] + wid * 1024 + lane * 16) = kv;
        *(uint4*)(vls[(c + 1) & 1] + wid * 1024 + lane * 16) = vv;
      }
    }
    // epilogue: ctx[b][t][h*64+dh] f16
    float inv = 1.0f / lsum;
    for (int r = 0; r < 4; ++r) {
      float ir = __shfl(inv, lq * 4 + r);
      int t = qw + lq * 4 + r;
      for (int nt = 0; nt < 4; ++nt)
        ctx[((size_t)(b * T_SEQ + t) * DM) + h * DH + nt * 16 + lm] = f2h(acc[nt][r] * ir);
    }
  }
}

extern "C" void kernel_launch(void* const* d_in, const int* in_sizes, int n_in,
                              void* d_out, int out_size, void* d_ws, size_t ws_size,
                              hipStream_t stream) {
  const float* q = (const float*)d_in[0];
  const float* k = (const float*)d_in[1];
  const float* v = (const float*)d_in[2];
  const float* attn_mask = (const float*)d_in[3];
  const float* Wq = (const float*)d_in[4];
  const float* Wk = (const float*)d_in[5];
  const float* Wv = (const float*)d_in[6];
  const float* Wo = (const float*)d_in[7];
  const int* mf = (const int*)d_in[8];

  u16* ws = (u16*)d_ws;
  u16* ctxb = ws;                     // f16 [8192][1024]
  u16* Qh  = ws + 8388608u;           // f16 [bh][t][64]
  u16* Kh  = Qh + 8388608u;           // f16 [bh][t][64]
  u16* VTh = Kh + 8388608u;           // f16 [bh][dh][2048]

  dim3 gq(64, 24);
  gemm_qkv<<<gq, 256, 0, stream>>>(q, k, v, Wq, Wk, Wv, Qh, Kh, VTh);

  attn_kernel<<<512, 512, 0, stream>>>(Qh, Kh, VTh, attn_mask, mf, ctxb);

  dim3 gg(64, 8);
  gemm_out<<<gg, 256, 0, stream>>>(ctxb, Wo, (float*)d_out);
}

// Round 10
// 394.132 us; speedup vs baseline: 1.0841x; 1.0828x over previous
//
#include <hip/hip_runtime.h>

typedef unsigned short u16;
typedef __attribute__((ext_vector_type(8))) _Float16 f16x8;
typedef __attribute__((ext_vector_type(2))) __fp16 fp16v2;
typedef __attribute__((ext_vector_type(4))) float f32x4;
typedef __attribute__((ext_vector_type(16))) float f32x16;

#define T_SEQ 2048
#define NH 16
#define DH 64
#define DM 1024
#define NEG2 (-14426.95f)      // NEG * log2(e)
#define QS2 (0.42466089f)      // 64^-0.25 * sqrt(log2(e))

__device__ __forceinline__ unsigned pk2(float a, float b) {
  union { fp16v2 v; unsigned u; } c;
  c.v = __builtin_amdgcn_cvt_pkrtz(a, b);
  return c.u;
}
__device__ __forceinline__ u16 f2h(float a) {
  union { _Float16 h; u16 u; } c; c.h = (_Float16)a; return c.u;
}

__device__ __forceinline__ void async_load16(const void* g, void* l) {
  __builtin_amdgcn_global_load_lds(
      (const __attribute__((address_space(1))) unsigned int*)(g),
      (__attribute__((address_space(3))) unsigned int*)(l), 16, 0, 0);
}

// LDS-only barrier: own-wave DS ops drained, global loads stay in flight.
__device__ __forceinline__ void lgkm_barrier() {
  asm volatile("s_waitcnt lgkmcnt(0)\n\ts_barrier" ::: "memory");
}

// ---------------- convert fp32 -> fp16 ----------------
__global__ __launch_bounds__(256) void convert_all(
    const float* __restrict__ q, const float* __restrict__ k, const float* __restrict__ v,
    const float* __restrict__ Wq, const float* __restrict__ Wk, const float* __restrict__ Wv,
    const float* __restrict__ Wo, u16* __restrict__ xb, u16* __restrict__ wb) {
  int blk = blockIdx.x;
  const float* src; u16* dst;
  if (blk < 12288) {
    int s = blk >> 12;
    src = (s == 0) ? q : (s == 1) ? k : v;
    dst = xb + (size_t)s * 8388608u;
    blk &= 4095;
  } else {
    int s = (blk - 12288) >> 9;
    src = (s == 0) ? Wq : (s == 1) ? Wk : (s == 2) ? Wv : Wo;
    dst = wb + (size_t)s * 1048576u;
    blk = (blk - 12288) & 511;
  }
  size_t base = (size_t)blk * 2048 + (size_t)threadIdx.x * 8;
  float4 a = *(const float4*)(src + base);
  float4 b2 = *(const float4*)(src + base + 4);
  uint4 st;
  st.x = pk2(a.x, a.y); st.y = pk2(a.z, a.w);
  st.z = pk2(b2.x, b2.y); st.w = pk2(b2.z, b2.w);
  *(uint4*)(dst + base) = st;
}

// ---------------- fused QKV projection GEMM ----------------
// fp16 in, 32x32x16 MFMA, BK=32, THREE LDS buffers, depth-2 DMA prefetch:
//   top of iter k:  s_waitcnt vmcnt(4) (k's 4 DMAs landed; k+1's in flight)
//                   s_barrier          (all waves' k-DMAs landed)
//                   issue k+2's DMAs   (safe: buf (k+2)%3 reads finished at k-1)
//                   compute k
// which<2 (Q/K): operands swapped (rows=channel), LDS-transpose epilogue -> [bh][t][dh].
// which==2 (V): normal, epilogue -> VT [bh][dh][t].
__global__ __launch_bounds__(256) void gemm_qkv(const u16* __restrict__ A,
                                                const u16* __restrict__ Wqb,
                                                const u16* __restrict__ Wkb,
                                                const u16* __restrict__ Wvb,
                                                u16* __restrict__ Qh, u16* __restrict__ Kh,
                                                u16* __restrict__ VTh) {
  __shared__ char lds[49152];  // 3 x (A 8KB + B 8KB); epilogue 128x264B aliases
  const int tid = threadIdx.x;
  const int wid = tid >> 6, lane = tid & 63;
  const int l32 = lane & 31, lh = lane >> 5;
  const int m0 = blockIdx.x * 128;
  const int n0 = blockIdx.y * 128;
  const int which = n0 >> 10;
  const int n0l = n0 & 1023;
  const u16* As = A + (size_t)which * 8388608u;
  const u16* Bw = (which == 0) ? Wqb : (which == 1) ? Wkb : Wvb;
  const int wm = wid >> 1, wn = wid & 1;
  f32x16 acc[2][2] = {};

  // cell (mt=wid, ks): A[m0+wid*32+l32][kt+ks*16+lh*8 ..+8]
  const u16* gA = As + (size_t)(m0 + wid * 32 + l32) * 1024 + lh * 8;
  const u16* gB = Bw + (size_t)(n0l + wid * 32 + l32) * 1024 + lh * 8;

#define STAGE(it2, buf)                                                   \
  do {                                                                    \
    int kt_ = (it2) * 32;                                                 \
    async_load16(gA + kt_, (buf) + (wid * 2 + 0) * 1024);                 \
    async_load16(gA + kt_ + 16, (buf) + (wid * 2 + 1) * 1024);            \
    async_load16(gB + kt_, (buf) + 8192 + (wid * 2 + 0) * 1024);          \
    async_load16(gB + kt_ + 16, (buf) + 8192 + (wid * 2 + 1) * 1024);     \
  } while (0)

  STAGE(0, lds);
  STAGE(1, lds + 16384);

  for (int it = 0; it < 32; ++it) {
    if (it == 31)
      asm volatile("s_waitcnt vmcnt(0)" ::: "memory");
    else
      asm volatile("s_waitcnt vmcnt(4)" ::: "memory");
    asm volatile("s_barrier" ::: "memory");
    char* cur = lds + (it % 3) * 16384;
    if (it + 2 < 32) STAGE(it + 2, lds + ((it + 2) % 3) * 16384);
    char* const rb = (which < 2) ? (cur + 8192) : cur;  // A-op: W for Q/K, X for V
    char* const cb = (which < 2) ? cur : (cur + 8192);
    for (int ks = 0; ks < 2; ++ks) {
      f16x8 rf[2], cf[2];
      for (int i = 0; i < 2; ++i) {
        rf[i] = *(const f16x8*)(rb + ((wm * 2 + i) * 2 + ks) * 1024 + lane * 16);
        cf[i] = *(const f16x8*)(cb + ((wn * 2 + i) * 2 + ks) * 1024 + lane * 16);
      }
      for (int i = 0; i < 2; ++i)
        for (int j = 0; j < 2; ++j)
          acc[i][j] = __builtin_amdgcn_mfma_f32_32x32x16_f16(rf[i], cf[j], acc[i][j], 0, 0, 0);
    }
  }
#undef STAGE

  // epilogue: C/D row = (reg&3)+8*(reg>>2)+4*lh, col = l32.
  const float s = (which < 2) ? QS2 : 1.0f;
  __syncthreads();
  for (int i = 0; i < 2; ++i)
    for (int j = 0; j < 2; ++j) {
      int colb = wn * 64 + j * 32 + l32;
      int rowb = wm * 64 + i * 32 + 4 * lh;
      for (int g = 0; g < 4; ++g) {
        uint2 pv;
        pv.x = pk2(acc[i][j][4 * g + 0] * s, acc[i][j][4 * g + 1] * s);
        pv.y = pk2(acc[i][j][4 * g + 2] * s, acc[i][j][4 * g + 3] * s);
        *(uint2*)(lds + colb * 264 + (rowb + 8 * g) * 2) = pv;
      }
    }
  __syncthreads();

  const int b = m0 >> 11, t0 = m0 & 2047, h0 = n0l >> 6;
  if (which < 2) {
    u16* O = which ? Kh : Qh;
    for (int p = 0; p < 8; ++p) {
      int row = p * 16 + (tid >> 4);  // t_local
      int seg = tid & 15;
      uint4 val = *(const uint4*)(lds + row * 264 + seg * 16);
      int hl = seg >> 3, dh0 = (seg & 7) * 8;
      *(uint4*)(O + (((size_t)(b * NH + h0 + hl) * T_SEQ + t0 + row) << 6) + dh0) = val;
    }
  } else {
    for (int p = 0; p < 8; ++p) {
      int row = p * 16 + (tid >> 4);  // ch_local
      int seg = tid & 15;
      uint4 val = *(const uint4*)(lds + row * 264 + seg * 16);
      int h = h0 + (row >> 6), dh = row & 63;
      *(uint4*)(VTh + (((size_t)(b * NH + h) * DH + dh) << 11) + t0 + seg * 8) = val;
    }
  }
}

// ---------------- output projection GEMM (fp32 out, same depth-2 pipeline) ----------------
__global__ __launch_bounds__(256) void gemm_out(const u16* __restrict__ A,
                                                const u16* __restrict__ Bw,
                                                float* __restrict__ O) {
  __shared__ char lds[49152];
  const int tid = threadIdx.x;
  const int wid = tid >> 6, lane = tid & 63;
  const int l32 = lane & 31, lh = lane >> 5;
  const int m0 = blockIdx.x * 128, n0 = blockIdx.y * 128;
  const int wm = wid >> 1, wn = wid & 1;
  f32x16 acc[2][2] = {};

  const u16* gA = A + (size_t)(m0 + wid * 32 + l32) * 1024 + lh * 8;
  const u16* gB = Bw + (size_t)(n0 + wid * 32 + l32) * 1024 + lh * 8;

#define STAGE(it2, buf)                                                   \
  do {                                                                    \
    int kt_ = (it2) * 32;                                                 \
    async_load16(gA + kt_, (buf) + (wid * 2 + 0) * 1024);                 \
    async_load16(gA + kt_ + 16, (buf) + (wid * 2 + 1) * 1024);            \
    async_load16(gB + kt_, (buf) + 8192 + (wid * 2 + 0) * 1024);          \
    async_load16(gB + kt_ + 16, (buf) + 8192 + (wid * 2 + 1) * 1024);     \
  } while (0)

  STAGE(0, lds);
  STAGE(1, lds + 16384);

  for (int it = 0; it < 32; ++it) {
    if (it == 31)
      asm volatile("s_waitcnt vmcnt(0)" ::: "memory");
    else
      asm volatile("s_waitcnt vmcnt(4)" ::: "memory");
    asm volatile("s_barrier" ::: "memory");
    char* cur = lds + (it % 3) * 16384;
    if (it + 2 < 32) STAGE(it + 2, lds + ((it + 2) % 3) * 16384);
    for (int ks = 0; ks < 2; ++ks) {
      f16x8 af[2], bf[2];
      for (int i = 0; i < 2; ++i) {
        af[i] = *(const f16x8*)(cur + ((wm * 2 + i) * 2 + ks) * 1024 + lane * 16);
        bf[i] = *(const f16x8*)(cur + 8192 + ((wn * 2 + i) * 2 + ks) * 1024 + lane * 16);
      }
      for (int i = 0; i < 2; ++i)
        for (int j = 0; j < 2; ++j)
          acc[i][j] = __builtin_amdgcn_mfma_f32_32x32x16_f16(af[i], bf[j], acc[i][j], 0, 0, 0);
    }
  }
#undef STAGE

  for (int i = 0; i < 2; ++i)
    for (int j = 0; j < 2; ++j) {
      int col = n0 + wn * 64 + j * 32 + l32;
      int rowb = m0 + wm * 64 + i * 32 + 4 * lh;
      for (int g = 0; g < 4; ++g)
        for (int rr = 0; rr < 4; ++rr)
          O[(size_t)(rowb + 8 * g + rr) * 1024 + col] = acc[i][j][4 * g + rr];
    }
}

// ---------------- Flash attention (S^T, fp16, 8 waves, depth-2 VGPR staging) ----------------
// Qh/Kh: f16 [bh][t][64] pre-scaled by QS2. VTh: f16 [bh][dh][t].
// ctx out: f16 [b][t][1024]. Block = 512 thr, q-tile 128; pair (p8, 15-p8).
// K/V: global->VGPR loads issued 2 chunks ahead; LDS buffers stay 2-deep.
__global__ __launch_bounds__(512) void attn_kernel(const u16* __restrict__ Qh,
                                                   const u16* __restrict__ Kh,
                                                   const u16* __restrict__ VTh,
                                                   const float* __restrict__ attn_mask,
                                                   const int* __restrict__ mfp,
                                                   u16* __restrict__ ctx) {
  __shared__ char kls[2][8192];   // K chunk (64s x 64k), cells (st*2+kk)
  __shared__ char vls[2][8192];   // V^T chunk (64dh x 64s), cells (nt*2+kk)
  __shared__ char pls[8][2048];   // per-wave P (16q x 64s) in A-frag order
  __shared__ u16 maskb[T_SEQ];    // pad bias in log2 domain (f16)
  __shared__ int mzf;

  const int tid = threadIdx.x;
  const int wid = tid >> 6, lane = tid & 63;
  const int lm = lane & 15, lq = lane >> 4;
  const int bid = blockIdx.x;
  const int bh_i = bid & 63, p8 = bid >> 6;
  const int b = bh_i >> 4, h = bh_i & 15;
  const int mf = *mfp;
  const size_t bh = (size_t)(b * NH + h);
  const u16* Qbh = Qh + bh * T_SEQ * DH;
  const u16* Kbh = Kh + bh * T_SEQ * DH;
  const u16* VTbh = VTh + bh * DH * T_SEQ;

  if (tid == 0) mzf = 0;
  __syncthreads();
  {
    int az = 0;
    for (int i = tid; i < T_SEQ; i += 512) {
      float mv = attn_mask[(size_t)b * T_SEQ + i];
      maskb[i] = f2h((mv == 0.0f) ? NEG2 : 0.0f);
      az |= (mv == 0.0f);
    }
    if (az) mzf = 1;  // benign same-value race
  }
  __syncthreads();
  const int maskzero = mzf;

  const int krow = (wid >> 1) * 16 + lm, koff = (wid & 1) * 32 + lq * 8;

  for (int half = 0; half < 2; ++half) {
    const int qt = half ? (15 - p8) : p8;
    const int q0 = qt * 128;
    const int qw = q0 + wid * 16;
    f16x8 qf[2];
    qf[0] = *(const f16x8*)(Qbh + (size_t)(qw + lm) * DH + lq * 8);
    qf[1] = *(const f16x8*)(Qbh + (size_t)(qw + lm) * DH + 32 + lq * 8);

    f32x4 acc[4] = {};
    float mprev = -1e30f, lsum = 0.f;

    const int nch = mf ? (qt + 1) * 2 : 32;
    // prologue: load chunks 0 and 1 into regs; write chunk 0 to buf 0
    uint4 kvr[2], vvr[2];
    kvr[0] = *(const uint4*)(Kbh + (size_t)krow * DH + koff);
    vvr[0] = *(const uint4*)(VTbh + (size_t)krow * T_SEQ + koff);
    if (nch > 1) {
      kvr[1] = *(const uint4*)(Kbh + (size_t)(64 + krow) * DH + koff);
      vvr[1] = *(const uint4*)(VTbh + (size_t)krow * T_SEQ + 64 + koff);
    }
    lgkm_barrier();  // prev half done reading kls/vls
    *(uint4*)(kls[0] + wid * 1024 + lane * 16) = kvr[0];
    *(uint4*)(vls[0] + wid * 1024 + lane * 16) = vvr[0];

    for (int c = 0; c < nch; ++c) {
      const int s0 = c * 64;
      if (c + 2 < nch) {  // depth-2: loads stay in flight across 2 chunk-times
        int s2 = s0 + 128;
        kvr[c & 1] = *(const uint4*)(Kbh + (size_t)(s2 + krow) * DH + koff);
        vvr[c & 1] = *(const uint4*)(VTbh + (size_t)krow * T_SEQ + s2 + koff);
      }
      lgkm_barrier();  // buf[c&1] staged (ds_writes drained block-wide)
      const char* kb = kls[c & 1];
      const char* vb = vls[c & 1];

      f32x4 sc[4];
      for (int st = 0; st < 4; ++st) {
        f32x4 z = {0.f, 0.f, 0.f, 0.f};
        sc[st] = z;
        for (int kk = 0; kk < 2; ++kk) {
          f16x8 kf = *(const f16x8*)(kb + ((st * 2 + kk) * 64 + lane) * 16);
          sc[st] = __builtin_amdgcn_mfma_f32_16x16x32_f16(kf, qf[kk], sc[st], 0, 0, 0);
        }
      }
      if (maskzero) {
        for (int st = 0; st < 4; ++st) {
          uint2 mraw = *(const uint2*)(maskb + s0 + st * 16 + lq * 4);
          const _Float16* mh = (const _Float16*)&mraw;
          for (int r = 0; r < 4; ++r) sc[st][r] += (float)mh[r];
        }
      }
      if (mf && (s0 + 64 > qw)) {
        int qg = qw + lm;
        for (int st = 0; st < 4; ++st)
          for (int r = 0; r < 4; ++r)
            if (s0 + st * 16 + lq * 4 + r > qg) sc[st][r] = NEG2;
      }
      float mx = fmaxf(fmaxf(sc[0][0], sc[0][1]), fmaxf(sc[0][2], sc[0][3]));
      for (int st = 1; st < 4; ++st) {
        float t2 = fmaxf(fmaxf(sc[st][0], sc[st][1]), fmaxf(sc[st][2], sc[st][3]));
        mx = fmaxf(mx, t2);
      }
      mx = fmaxf(mx, __shfl_xor(mx, 16));
      mx = fmaxf(mx, __shfl_xor(mx, 32));
      float mn = mprev;
      if (__ballot(mx > mprev) != 0ull) {
        mn = fmaxf(mprev, mx);
        float alpha = exp2f(mprev - mn);
        for (int r = 0; r < 4; ++r) {
          float ar = __shfl(alpha, lq * 4 + r);
          for (int nt = 0; nt < 4; ++nt) acc[nt][r] *= ar;
        }
        lsum *= alpha;
        mprev = mn;
      }
      float ps = 0.f;
      for (int st = 0; st < 4; ++st)
        for (int r = 0; r < 4; ++r) {
          float p = exp2f(sc[st][r] - mn);
          sc[st][r] = p;
          ps += p;
        }
      ps += __shfl_xor(ps, 16);
      ps += __shfl_xor(ps, 32);
      lsum += ps;
      {
        char* pw = pls[wid];
        for (int st = 0; st < 4; ++st) {
          int kk = st >> 1;
          int lqp = (st & 1) * 2 + (lq >> 1);
          uint2 pv;
          pv.x = pk2(sc[st][0], sc[st][1]);
          pv.y = pk2(sc[st][2], sc[st][3]);
          *(uint2*)(pw + kk * 1024 + (lqp * 16 + lm) * 16 + (lq & 1) * 8) = pv;
        }
      }
      asm volatile("s_waitcnt lgkmcnt(0)" ::: "memory");
      for (int kk = 0; kk < 2; ++kk) {
        f16x8 pf = *(const f16x8*)(pls[wid] + kk * 1024 + lane * 16);
        for (int nt = 0; nt < 4; ++nt) {
          f16x8 vf = *(const f16x8*)(vb + ((nt * 2 + kk) * 64 + lane) * 16);
          acc[nt] = __builtin_amdgcn_mfma_f32_16x16x32_f16(pf, vf, acc[nt], 0, 0, 0);
        }
      }
      if (c + 1 < nch) {  // stage chunk c+1 (held in regs since c-1)
        *(uint4*)(kls[(c + 1) & 1] + wid * 1024 + lane * 16) = kvr[(c + 1) & 1];
        *(uint4*)(vls[(c + 1) & 1] + wid * 1024 + lane * 16) = vvr[(c + 1) & 1];
      }
    }
    float inv = 1.0f / lsum;
    for (int r = 0; r < 4; ++r) {
      float ir = __shfl(inv, lq * 4 + r);
      int t = qw + lq * 4 + r;
      for (int nt = 0; nt < 4; ++nt)
        ctx[((size_t)(b * T_SEQ + t) * DM) + h * DH + nt * 16 + lm] = f2h(acc[nt][r] * ir);
    }
  }
}

extern "C" void kernel_launch(void* const* d_in, const int* in_sizes, int n_in,
                              void* d_out, int out_size, void* d_ws, size_t ws_size,
                              hipStream_t stream) {
  const float* q = (const float*)d_in[0];
  const float* k = (const float*)d_in[1];
  const float* v = (const float*)d_in[2];
  const float* attn_mask = (const float*)d_in[3];
  const float* Wq = (const float*)d_in[4];
  const float* Wk = (const float*)d_in[5];
  const float* Wv = (const float*)d_in[6];
  const float* Wo = (const float*)d_in[7];
  const int* mf = (const int*)d_in[8];

  u16* ws = (u16*)d_ws;
  u16* qb  = ws;                      // f16 inputs [8192,1024] x3 (q,k,v contiguous)
  u16* wqb = ws + 3u * 8388608u;      // f16 weights x4
  u16* wkb = wqb + 1048576u;
  u16* wvb = wkb + 1048576u;
  u16* wob = wvb + 1048576u;
  u16* Qh  = wob + 1048576u;          // [bh][t][64]
  u16* Kh  = Qh + 8388608u;           // [bh][t][64]
  u16* VTh = Kh + 8388608u;           // [bh][dh][2048]
  u16* ctxb = ws;                     // alias over qb (dead after projections)

  convert_all<<<14336, 256, 0, stream>>>(q, k, v, Wq, Wk, Wv, Wo, qb, wqb);

  dim3 gq(64, 24);
  gemm_qkv<<<gq, 256, 0, stream>>>(qb, wqb, wkb, wvb, Qh, Kh, VTh);

  attn_kernel<<<512, 512, 0, stream>>>(Qh, Kh, VTh, attn_mask, mf, ctxb);

  dim3 gg(64, 8);
  gemm_out<<<gg, 256, 0, stream>>>(ctxb, wob, (float*)d_out);
}